// Round 12
// baseline (407.507 us; speedup 1.0000x reference)
//
#include <hip/hip_runtime.h>

typedef __attribute__((ext_vector_type(8))) short short8;
typedef __attribute__((ext_vector_type(4))) float f32x4;
typedef unsigned short u16;
typedef unsigned int u32;

#define CNT_PER_C (8*64*32*32)   // 524288

// workspace offsets (bytes)
#define WS_PART  0          // 8 shards x 256 f32 = 8192 B
#define WS_BIAS  9216       // 192 f32 (K,Q,V row biases)
#define WS_WKQV  10240      // 192*128 bf16 (scale-folded)
#define WS_WO    59392      // 128*64 bf16
#define WS_XT    131072     // 8192*8192 bf16 = 134 MB (raw transposed x)

__device__ __forceinline__ u16 f2bf(float f){
  u32 u = __builtin_bit_cast(u32, f);
  u32 r = u + 0x7FFFu + ((u >> 16) & 1u);
  return (u16)(r >> 16);
}
__device__ __forceinline__ float bf2f(u16 h){
  u32 u = ((u32)h) << 16;
  return __builtin_bit_cast(float, u);
}
// pack two f32 -> two bf16 in one u32 (lo = a, hi = b); pure C
__device__ __forceinline__ u32 pk2(float a, float b){
  return (u32)f2bf(a) | ((u32)f2bf(b) << 16);
}

// ---------------- K0: zero the stats shards (ws is poisoned, not re-zeroed) ----------------
__global__ void k_zero(float* part){
  part[blockIdx.x*256 + threadIdx.x] = 0.f;   // <<<8,256>>> covers 2048 f32
}

// ---------------- K1: fused stats + transpose: x -> x_t[n][d][c] bf16 (RAW) + per-c sums ----
__global__ __launch_bounds__(256) void k_stats_t(const float* __restrict__ x,
                                                 u16* __restrict__ x_t,
                                                 float* __restrict__ part){
  __shared__ u16 lm[32*512];           // 32 KB
  __shared__ float cs[256];            // [c*2 + {sum,sumsq}]
  int t = threadIdx.x;
  cs[t] = 0.f;
  int bid = blockIdx.x;
  int bh = bid>>3, dq = bid&7;
  int b = bh>>5, h = bh&31;
  int d0 = dq*8, n0 = bh*32;
  int s = t>>3, q = t&7;
  float sA=0.f,qA=0.f, sB=0.f,qB=0.f, sC=0.f,qC=0.f, sD=0.f,qD=0.f;
  __syncthreads();
#pragma unroll
  for (int h2=0; h2<2; h2++){
    int w4 = q*4;
#pragma unroll
    for (int i=0;i<16;i++){
      int rowpos = i*32 + s;
      int cl = rowpos & 63, dd = rowpos >> 6;
      int c = h2*64 + cl;
      float4 v = *(const float4*)(x + ((size_t)((b*128 + c)*64 + d0 + dd))*1024 + h*32 + w4);
      float lsum = v.x+v.y+v.z+v.w;
      float lsq  = v.x*v.x+v.y*v.y+v.z*v.z+v.w*v.w;
      if (h2==0){ if ((i&1)==0){ sA+=lsum; qA+=lsq; } else { sB+=lsum; qB+=lsq; } }
      else      { if ((i&1)==0){ sC+=lsum; qC+=lsq; } else { sD+=lsum; qD+=lsq; } }
      lm[(w4+0)*512 + (rowpos ^ ((w4+0)&28))] = f2bf(v.x);
      lm[(w4+1)*512 + (rowpos ^ ((w4+1)&28))] = f2bf(v.y);
      lm[(w4+2)*512 + (rowpos ^ ((w4+2)&28))] = f2bf(v.z);
      lm[(w4+3)*512 + (rowpos ^ ((w4+3)&28))] = f2bf(v.w);
    }
    __syncthreads();
    {
      int n = s, oct = q;
      int oq = oct ^ ((n>>3)&3);
      bool swp = (n & 4) != 0;
#pragma unroll
      for (int m=0;m<8;m++){
        uint4 raw = *(const uint4*)&lm[n*512 + m*64 + oq*8];
        if (swp){ u32 tx=raw.x, ty=raw.y; raw.x=raw.z; raw.y=raw.w; raw.z=tx; raw.w=ty; }
        *(uint4*)(x_t + (size_t)(n0+n)*8192 + (size_t)(d0+m)*128 + h2*64 + oct*8) = raw;
      }
    }
    __syncthreads();
  }
  atomicAdd(&cs[(s    )*2+0], sA); atomicAdd(&cs[(s    )*2+1], qA);
  atomicAdd(&cs[(s+32 )*2+0], sB); atomicAdd(&cs[(s+32 )*2+1], qB);
  atomicAdd(&cs[(s+64 )*2+0], sC); atomicAdd(&cs[(s+64 )*2+1], qC);
  atomicAdd(&cs[(s+96 )*2+0], sD); atomicAdd(&cs[(s+96 )*2+1], qD);
  __syncthreads();
  atomicAdd(&part[(bid&7)*256 + t], cs[t]);
}

// ---------------- K2: finalize stats + fold BN into weights (fused stats2+wprep) ----------------
__global__ __launch_bounds__(256) void k_finalize(const float* part, const float* gamma,
                                                  const float* beta, const float* wk,
                                                  const float* wq, const float* wv,
                                                  const float* wo, u16* wkqv_bf, u16* wo_bf,
                                                  float* bias){
  __shared__ float lsc[128], lsh[128];
  int t = threadIdx.x;
  if (t < 128){
    float S=0.f, S2=0.f;
    for (int i=0;i<8;i++){ S += part[i*256 + t*2]; S2 += part[i*256 + t*2 + 1]; }
    float inv = 1.0f/(float)CNT_PER_C;
    float mean = S*inv;
    float var  = S2*inv - mean*mean;
    float rstd = rsqrtf(var + 1e-5f);
    float sc = gamma[t]*rstd;
    lsc[t] = sc; lsh[t] = beta[t] - mean*sc;
  }
  __syncthreads();
  if (t < 192){
    const float* src = (t<64) ? (wk + t*128) : (t<128) ? (wq + (t-64)*128) : (wv + (t-128)*128);
    float bsum = 0.f;
    for (int c=0;c<128;c++){
      float w = src[c];
      bsum += w*lsh[c];
      wkqv_bf[t*128+c] = f2bf(w*lsc[c]);
    }
    bias[t] = bsum;
  }
  for (int j=t; j<8192; j+=256) wo_bf[j] = f2bf(wo[j]);
}

// ---------------- K3: per-wave fused attention + DIRECT final BCDHW write ----------------
// Block p -> bh=(p&7)*32+(p>>6), wg=(p>>3)&7: the 8 wg-siblings of a bh share p%8
// (same XCD) and sit within one 64-block dispatch window, so their partial 16B line
// writes merge in that XCD's L2. Wave wid owns n = bh*32 + wg*4 + wid.
// Per-wave body identical to R11 (proven). Epilogue: block barrier, then 256 threads
// gather 4 w-values per (c,d) from the 4 slots and store float4 to out.
__global__ __launch_bounds__(256, 2) void k_attn_w(const u16* __restrict__ x_t,
                                                   const u16* __restrict__ wkqv,
                                                   const u16* __restrict__ wo,
                                                   const float* __restrict__ bias,
                                                   float* __restrict__ out){
  __shared__ alignas(16) char smb[65536];   // 4 x 16 KB
  const int t = threadIdx.x, lane = t & 63, wid = t >> 6;
  const int lr = lane & 15, lk = lane >> 4;
  const int p = blockIdx.x;
  const int bh = (p & 7)*32 + (p >> 6);
  const int wg = (p >> 3) & 7;
  const int b = bh >> 5, h = bh & 31;
  const int n = bh*32 + wg*4 + wid;
  char* slot = smb + wid*16384;
  char* lo = slot;
  char* hi = slot + 8192;
  const u16* xg = x_t + (size_t)n*8192;

  // ---- x B-fragments direct from global ----
  short8 xbf[4][4];
#pragma unroll
  for (int ct=0; ct<4; ct++)
#pragma unroll
    for (int ks=0; ks<4; ks++)
      xbf[ct][ks] = *(const short8*)(xg + (ct*16+lr)*128 + ks*32 + lk*8);

  // ---- GEMM1-K: C[s][d] -> kt[d][s] (lo), +bias ----
#pragma unroll
  for (int mt=0; mt<4; mt++){
    short8 af[4];
#pragma unroll
    for (int ks=0; ks<4; ks++)
      af[ks] = *(const short8*)(wkqv + (size_t)(mt*16 + lr)*128 + ks*32 + lk*8);
    float4 bk4 = *(const float4*)(bias + mt*16 + lk*4);
#pragma unroll
    for (int ct=0; ct<4; ct++){
      f32x4 a = (f32x4){0.f,0.f,0.f,0.f};
#pragma unroll
      for (int ks=0; ks<4; ks++)
        a = __builtin_amdgcn_mfma_f32_16x16x32_bf16(af[ks], xbf[ct][ks], a, 0,0,0);
      a[0]+=bk4.x; a[1]+=bk4.y; a[2]+=bk4.z; a[3]+=bk4.w;
      int d = ct*16 + lr;
      *(uint2*)(lo + d*128 + ((mt*32 + lk*8) ^ ((d&7)<<4))) =
        (uint2){pk2(a[0],a[1]), pk2(a[2],a[3])};
    }
  }
  // ---- GEMM1-Q: C[s][j] -> qt[j][s] (hi), +bias ----
#pragma unroll
  for (int mt=0; mt<4; mt++){
    short8 af[4];
#pragma unroll
    for (int ks=0; ks<4; ks++)
      af[ks] = *(const short8*)(wkqv + (size_t)((mt+4)*16 + lr)*128 + ks*32 + lk*8);
    float4 bq4 = *(const float4*)(bias + 64 + mt*16 + lk*4);
#pragma unroll
    for (int ct=0; ct<4; ct++){
      f32x4 a = (f32x4){0.f,0.f,0.f,0.f};
#pragma unroll
      for (int ks=0; ks<4; ks++)
        a = __builtin_amdgcn_mfma_f32_16x16x32_bf16(af[ks], xbf[ct][ks], a, 0,0,0);
      a[0]+=bq4.x; a[1]+=bq4.y; a[2]+=bq4.z; a[3]+=bq4.w;
      int d = ct*16 + lr;
      *(uint2*)(hi + d*128 + ((mt*32 + lk*8) ^ ((d&7)<<4))) =
        (uint2){pk2(a[0],a[1]), pk2(a[2],a[3])};
    }
  }
  // ---- GEMM1-V -> registers, +bias ----
  f32x4 vacc[4][4];
#pragma unroll
  for (int mt=0; mt<4; mt++){
    short8 af[4];
#pragma unroll
    for (int ks=0; ks<4; ks++)
      af[ks] = *(const short8*)(wkqv + (size_t)((mt+8)*16 + lr)*128 + ks*32 + lk*8);
    float4 bv4 = *(const float4*)(bias + 128 + mt*16 + lk*4);
#pragma unroll
    for (int ct=0; ct<4; ct++) vacc[mt][ct] = (f32x4){0.f,0.f,0.f,0.f};
#pragma unroll
    for (int ct=0; ct<4; ct++){
#pragma unroll
      for (int ks=0; ks<4; ks++)
        vacc[mt][ct] = __builtin_amdgcn_mfma_f32_16x16x32_bf16(af[ks], xbf[ct][ks], vacc[mt][ct], 0,0,0);
      vacc[mt][ct][0]+=bv4.x; vacc[mt][ct][1]+=bv4.y;
      vacc[mt][ct][2]+=bv4.z; vacc[mt][ct][3]+=bv4.w;
    }
  }

  // ---- ka frags from kt (before V overwrites lo) ----
  short8 ka[4][2];
#pragma unroll
  for (int it=0; it<4; it++)
#pragma unroll
    for (int ks2=0; ks2<2; ks2++){
      int i = it*16 + lr;
      ka[it][ks2] = *(const short8*)(lo + i*128 + ((ks2*64 + lk*16) ^ ((i&7)<<4)));
    }
  // ---- scatter V -> vt[s'][i] (lo), scalar ----
#pragma unroll
  for (int m4=0; m4<4; m4++)
#pragma unroll
    for (int ct=0; ct<4; ct++)
#pragma unroll
      for (int e=0; e<4; e++){
        int sp = m4*16 + lk*4 + e, i = ct*16 + lr;
        *(u16*)(lo + sp*128 + ((i*2) ^ ((sp&7)<<4))) = f2bf(vacc[m4][ct][e]);
      }
  short8 qb[4][2];
#pragma unroll
  for (int jt=0; jt<4; jt++)
#pragma unroll
    for (int ks2=0; ks2<2; ks2++){
      int j = jt*16 + lr;
      qb[jt][ks2] = *(const short8*)(hi + j*128 + ((ks2*64 + lk*16) ^ ((j&7)<<4)));
    }
  // ---- GEMM2: scores[i][j] ----
  f32x4 sc4[4][4];
#pragma unroll
  for (int it=0; it<4; it++)
#pragma unroll
    for (int jt=0; jt<4; jt++) sc4[it][jt] = (f32x4){0.f,0.f,0.f,0.f};
#pragma unroll
  for (int it=0; it<4; it++)
#pragma unroll
    for (int jt=0; jt<4; jt++)
#pragma unroll
      for (int ks2=0; ks2<2; ks2++)
        sc4[it][jt] = __builtin_amdgcn_mfma_f32_16x16x32_bf16(ka[it][ks2], qb[jt][ks2], sc4[it][jt], 0,0,0);

  // ---- softmax over i per column j -> a_t[j][i] (hi) ----
#pragma unroll
  for (int jt=0; jt<4; jt++){
    float m = -1e30f;
#pragma unroll
    for (int it=0; it<4; it++)
#pragma unroll
      for (int e=0; e<4; e++) m = fmaxf(m, sc4[it][jt][e]);
    m = fmaxf(m, __shfl_xor(m, 16, 64));
    m = fmaxf(m, __shfl_xor(m, 32, 64));
    float ssum = 0.f;
#pragma unroll
    for (int it=0; it<4; it++)
#pragma unroll
      for (int e=0; e<4; e++){
        float pp = __expf((sc4[it][jt][e] - m) * 0.125f);
        sc4[it][jt][e] = pp; ssum += pp;
      }
    ssum += __shfl_xor(ssum, 16, 64);
    ssum += __shfl_xor(ssum, 32, 64);
    float inv = 1.0f / ssum;
    int j = jt*16 + lr;
#pragma unroll
    for (int it=0; it<4; it++){
      *(uint2*)(hi + j*128 + ((it*32 + lk*8) ^ ((j&7)<<4))) =
        (uint2){pk2(sc4[it][jt][0]*inv, sc4[it][jt][1]*inv),
                pk2(sc4[it][jt][2]*inv, sc4[it][jt][3]*inv)};
    }
  }

  // ---- GEMM3: attn[s'][j] -> attn_t[d=j][s'] (lo) ----
  short8 va[4][2], ab[4][2];
#pragma unroll
  for (int st=0; st<4; st++)
#pragma unroll
    for (int ks2=0; ks2<2; ks2++){
      int s2 = st*16 + lr;
      va[st][ks2] = *(const short8*)(lo + s2*128 + ((ks2*64 + lk*16) ^ ((s2&7)<<4)));
    }
#pragma unroll
  for (int jt=0; jt<4; jt++)
#pragma unroll
    for (int ks2=0; ks2<2; ks2++){
      int j = jt*16 + lr;
      ab[jt][ks2] = *(const short8*)(hi + j*128 + ((ks2*64 + lk*16) ^ ((j&7)<<4)));
    }
  f32x4 at4[4][4];
#pragma unroll
  for (int st=0; st<4; st++)
#pragma unroll
    for (int jt=0; jt<4; jt++) at4[st][jt] = (f32x4){0.f,0.f,0.f,0.f};
#pragma unroll
  for (int st=0; st<4; st++)
#pragma unroll
    for (int jt=0; jt<4; jt++)
#pragma unroll
      for (int ks2=0; ks2<2; ks2++)
        at4[st][jt] = __builtin_amdgcn_mfma_f32_16x16x32_bf16(va[st][ks2], ab[jt][ks2], at4[st][jt], 0,0,0);
#pragma unroll
  for (int st=0; st<4; st++)
#pragma unroll
    for (int jt=0; jt<4; jt++){
      int d = jt*16 + lr;
      *(uint2*)(lo + d*128 + ((st*32 + lk*8) ^ ((d&7)<<4))) =
        (uint2){pk2(at4[st][jt][0], at4[st][jt][1]), pk2(at4[st][jt][2], at4[st][jt][3])};
    }

  // ---- GEMM4 + residual -> o_slab[c][d] in slot ----
  short8 tb[4][2];
#pragma unroll
  for (int dt=0; dt<4; dt++)
#pragma unroll
    for (int ks2=0; ks2<2; ks2++){
      int d = dt*16 + lr;
      tb[dt][ks2] = *(const short8*)(lo + d*128 + ((ks2*64 + lk*16) ^ ((d&7)<<4)));
    }
#pragma unroll
  for (int mt=0; mt<8; mt++){
    short8 wa[2];
#pragma unroll
    for (int ks2=0; ks2<2; ks2++)
      wa[ks2] = *(const short8*)(wo + (size_t)(mt*16 + lr)*64 + ks2*32 + lk*8);
    f32x4 oa[4];
#pragma unroll
    for (int dt=0; dt<4; dt++) oa[dt] = (f32x4){0.f,0.f,0.f,0.f};
#pragma unroll
    for (int dt=0; dt<4; dt++)
#pragma unroll
      for (int ks2=0; ks2<2; ks2++)
        oa[dt] = __builtin_amdgcn_mfma_f32_16x16x32_bf16(wa[ks2], tb[dt][ks2], oa[dt], 0,0,0);
#pragma unroll
    for (int dt=0; dt<4; dt++){
      ushort4 xv = *(const ushort4*)(xg + (size_t)(dt*16+lr)*128 + mt*16 + lk*4);
      oa[dt][0] += bf2f(xv.x);
      oa[dt][1] += bf2f(xv.y);
      oa[dt][2] += bf2f(xv.z);
      oa[dt][3] += bf2f(xv.w);
    }
#pragma unroll
    for (int dt=0; dt<4; dt++)
#pragma unroll
      for (int e=0; e<4; e++){
        int cc = mt*16 + lk*4 + e, d = dt*16 + lr;
        *(u16*)(slot + cc*128 + ((d*2) ^ ((cc&7)<<4))) = f2bf(oa[dt][e]);
      }
  }

  // ---- block-wide gather across the 4 slots -> direct float4 store to out ----
  __syncthreads();
  const int w0 = wg*4;
#pragma unroll
  for (int i=0; i<32; i++){
    int c = i*4 + wid;        // wave wid covers c ≡ wid (mod 4)
    int d = lane;             // 64 lanes = all d
    int off = c*128 + ((d*2) ^ ((c&7)<<4));
    float4 ov;
    ov.x = bf2f(*(const u16*)(smb +     0 + off));
    ov.y = bf2f(*(const u16*)(smb + 16384 + off));
    ov.z = bf2f(*(const u16*)(smb + 32768 + off));
    ov.w = bf2f(*(const u16*)(smb + 49152 + off));
    *(float4*)(out + ((size_t)((b*128+c)*64) + d)*1024 + h*32 + w0) = ov;
  }
}

extern "C" void kernel_launch(void* const* d_in, const int* in_sizes, int n_in,
                              void* d_out, int out_size, void* d_ws, size_t ws_size,
                              hipStream_t stream){
  const float* x     = (const float*)d_in[0];
  const float* Wk    = (const float*)d_in[1];
  const float* Wq    = (const float*)d_in[2];
  const float* Wv    = (const float*)d_in[3];
  const float* Wo    = (const float*)d_in[4];
  const float* gamma = (const float*)d_in[5];
  const float* beta  = (const float*)d_in[6];
  float* out = (float*)d_out;
  char* ws = (char*)d_ws;

  float* part  = (float*)(ws + WS_PART);
  float* bias  = (float*)(ws + WS_BIAS);
  u16* wkqv  = (u16*)(ws + WS_WKQV);
  u16* wo_bf = (u16*)(ws + WS_WO);
  u16* x_t   = (u16*)(ws + WS_XT);   // moved to ws: out is now written directly by k_attn_w

  k_zero    <<<8,    256, 0, stream>>>(part);
  k_stats_t <<<2048, 256, 0, stream>>>(x, x_t, part);
  k_finalize<<<1,    256, 0, stream>>>(part, gamma, beta, Wk, Wq, Wv, Wo, wkqv, wo_bf, bias);
  k_attn_w  <<<2048, 256, 0, stream>>>(x_t, wkqv, wo_bf, bias, out);
}

// Round 13
// 322.459 us; speedup vs baseline: 1.2637x; 1.2637x over previous
//
#include <hip/hip_runtime.h>

typedef __attribute__((ext_vector_type(8))) short short8;
typedef __attribute__((ext_vector_type(4))) float f32x4;
typedef unsigned short u16;
typedef unsigned int u32;

#define CNT_PER_C (8*64*32*32)   // 524288

// workspace offsets (bytes)
#define WS_PART  0          // 8 shards x 256 f32 = 8192 B
#define WS_BIAS  9216       // 192 f32 (K,Q,V row biases)
#define WS_WKQV  10240      // 192*128 bf16 (scale-folded)
#define WS_WO    59392      // 128*64 bf16
#define WS_OUTP  131072     // 8192*8192 bf16 = 134 MB

__device__ __forceinline__ u16 f2bf(float f){
  u32 u = __builtin_bit_cast(u32, f);
  u32 r = u + 0x7FFFu + ((u >> 16) & 1u);
  return (u16)(r >> 16);
}
__device__ __forceinline__ float bf2f(u16 h){
  u32 u = ((u32)h) << 16;
  return __builtin_bit_cast(float, u);
}
// pack two f32 -> two bf16 in one u32 (lo = a, hi = b); pure C
__device__ __forceinline__ u32 pk2(float a, float b){
  return (u32)f2bf(a) | ((u32)f2bf(b) << 16);
}

// ---------------- K0: zero the stats shards (ws is poisoned, not re-zeroed) ----------------
__global__ void k_zero(float* part){
  part[blockIdx.x*256 + threadIdx.x] = 0.f;   // <<<8,256>>> covers 2048 f32
}

// ---------------- K1: fused stats + transpose: x -> x_t[n][d][c] bf16 (RAW) + per-c sums ----
__global__ __launch_bounds__(256) void k_stats_t(const float* __restrict__ x,
                                                 u16* __restrict__ x_t,
                                                 float* __restrict__ part){
  __shared__ u16 lm[32*512];           // 32 KB
  __shared__ float cs[256];            // [c*2 + {sum,sumsq}]
  int t = threadIdx.x;
  cs[t] = 0.f;
  int bid = blockIdx.x;
  int bh = bid>>3, dq = bid&7;
  int b = bh>>5, h = bh&31;
  int d0 = dq*8, n0 = bh*32;
  int s = t>>3, q = t&7;
  float sA=0.f,qA=0.f, sB=0.f,qB=0.f, sC=0.f,qC=0.f, sD=0.f,qD=0.f;
  __syncthreads();
#pragma unroll
  for (int h2=0; h2<2; h2++){
    int w4 = q*4;
#pragma unroll
    for (int i=0;i<16;i++){
      int rowpos = i*32 + s;
      int cl = rowpos & 63, dd = rowpos >> 6;
      int c = h2*64 + cl;
      float4 v = *(const float4*)(x + ((size_t)((b*128 + c)*64 + d0 + dd))*1024 + h*32 + w4);
      float lsum = v.x+v.y+v.z+v.w;
      float lsq  = v.x*v.x+v.y*v.y+v.z*v.z+v.w*v.w;
      if (h2==0){ if ((i&1)==0){ sA+=lsum; qA+=lsq; } else { sB+=lsum; qB+=lsq; } }
      else      { if ((i&1)==0){ sC+=lsum; qC+=lsq; } else { sD+=lsum; qD+=lsq; } }
      lm[(w4+0)*512 + (rowpos ^ ((w4+0)&28))] = f2bf(v.x);
      lm[(w4+1)*512 + (rowpos ^ ((w4+1)&28))] = f2bf(v.y);
      lm[(w4+2)*512 + (rowpos ^ ((w4+2)&28))] = f2bf(v.z);
      lm[(w4+3)*512 + (rowpos ^ ((w4+3)&28))] = f2bf(v.w);
    }
    __syncthreads();
    {
      int n = s, oct = q;
      int oq = oct ^ ((n>>3)&3);
      bool swp = (n & 4) != 0;
#pragma unroll
      for (int m=0;m<8;m++){
        uint4 raw = *(const uint4*)&lm[n*512 + m*64 + oq*8];
        if (swp){ u32 tx=raw.x, ty=raw.y; raw.x=raw.z; raw.y=raw.w; raw.z=tx; raw.w=ty; }
        *(uint4*)(x_t + (size_t)(n0+n)*8192 + (size_t)(d0+m)*128 + h2*64 + oct*8) = raw;
      }
    }
    __syncthreads();
  }
  atomicAdd(&cs[(s    )*2+0], sA); atomicAdd(&cs[(s    )*2+1], qA);
  atomicAdd(&cs[(s+32 )*2+0], sB); atomicAdd(&cs[(s+32 )*2+1], qB);
  atomicAdd(&cs[(s+64 )*2+0], sC); atomicAdd(&cs[(s+64 )*2+1], qC);
  atomicAdd(&cs[(s+96 )*2+0], sD); atomicAdd(&cs[(s+96 )*2+1], qD);
  __syncthreads();
  atomicAdd(&part[(bid&7)*256 + t], cs[t]);
}

// ---------------- K2: finalize stats + fold BN into weights ----------------
__global__ __launch_bounds__(256) void k_finalize(const float* part, const float* gamma,
                                                  const float* beta, const float* wk,
                                                  const float* wq, const float* wv,
                                                  const float* wo, u16* wkqv_bf, u16* wo_bf,
                                                  float* bias){
  __shared__ float lsc[128], lsh[128];
  int t = threadIdx.x;
  if (t < 128){
    float S=0.f, S2=0.f;
    for (int i=0;i<8;i++){ S += part[i*256 + t*2]; S2 += part[i*256 + t*2 + 1]; }
    float inv = 1.0f/(float)CNT_PER_C;
    float mean = S*inv;
    float var  = S2*inv - mean*mean;
    float rstd = rsqrtf(var + 1e-5f);
    float sc = gamma[t]*rstd;
    lsc[t] = sc; lsh[t] = beta[t] - mean*sc;
  }
  __syncthreads();
  if (t < 192){
    const float* src = (t<64) ? (wk + t*128) : (t<128) ? (wq + (t-64)*128) : (wv + (t-128)*128);
    float bsum = 0.f;
    for (int c=0;c<128;c++){
      float w = src[c];
      bsum += w*lsh[c];
      wkqv_bf[t*128+c] = f2bf(w*lsc[c]);
    }
    bias[t] = bsum;
  }
  for (int j=t; j<8192; j+=256) wo_bf[j] = f2bf(wo[j]);
}

// ---------------- K3: per-wave fused attention, 8 KB/wave slot, natural VGPR ----------------
// 4 waves/block, wave wid owns n = bid*4+wid; ONE 8 KB buffer (64 rows x 128B,
// byte ^ ((row&7)<<4) swizzle) time-multiplexed (R9-proven ordering):
//   kt -> (ka) -> qt -> (qb) -> V(regs)->vt -> GEMM2 -> softmax(in-reg) -> (va)
//   -> a_t -> (ab) -> GEMM3 -> attn_t -> (tb) -> GEMM4+residual in 2 c-halves -> store.
// __launch_bounds__(256,2): natural ~100 VGPR (no R9 spill); 32 KB LDS -> 4-5 blocks/CU.
__global__ __launch_bounds__(256, 2) void k_attn(const u16* __restrict__ x_t,
                                                 const u16* __restrict__ wkqv,
                                                 const u16* __restrict__ wo,
                                                 const float* __restrict__ bias,
                                                 u16* __restrict__ out_pre){
  __shared__ alignas(16) char smb[32768];   // 4 x 8 KB
  const int t = threadIdx.x, lane = t & 63, wid = t >> 6;
  const int lr = lane & 15, lk = lane >> 4;
  const int n = blockIdx.x*4 + wid;
  char* slot = smb + wid*8192;
  const u16* xg = x_t + (size_t)n*8192;

  // ---- x B-fragments direct from global ----
  short8 xbf[4][4];
#pragma unroll
  for (int ct=0; ct<4; ct++)
#pragma unroll
    for (int ks=0; ks<4; ks++)
      xbf[ct][ks] = *(const short8*)(xg + (ct*16+lr)*128 + ks*32 + lk*8);

  // ---- GEMM1-K: C[s][d] -> kt[d][s], +bias ----
#pragma unroll
  for (int mt=0; mt<4; mt++){
    short8 af[4];
#pragma unroll
    for (int ks=0; ks<4; ks++)
      af[ks] = *(const short8*)(wkqv + (size_t)(mt*16 + lr)*128 + ks*32 + lk*8);
    float4 bk4 = *(const float4*)(bias + mt*16 + lk*4);
#pragma unroll
    for (int ct=0; ct<4; ct++){
      f32x4 a = (f32x4){0.f,0.f,0.f,0.f};
#pragma unroll
      for (int ks=0; ks<4; ks++)
        a = __builtin_amdgcn_mfma_f32_16x16x32_bf16(af[ks], xbf[ct][ks], a, 0,0,0);
      a[0]+=bk4.x; a[1]+=bk4.y; a[2]+=bk4.z; a[3]+=bk4.w;
      int d = ct*16 + lr;
      *(uint2*)(slot + d*128 + ((mt*32 + lk*8) ^ ((d&7)<<4))) =
        (uint2){pk2(a[0],a[1]), pk2(a[2],a[3])};
    }
  }
  // ---- ka frags from kt ----
  short8 ka[4][2];
#pragma unroll
  for (int it=0; it<4; it++)
#pragma unroll
    for (int ks2=0; ks2<2; ks2++){
      int i = it*16 + lr;
      ka[it][ks2] = *(const short8*)(slot + i*128 + ((ks2*64 + lk*16) ^ ((i&7)<<4)));
    }

  // ---- GEMM1-Q: C[s][j] -> qt[j][s] (overwrites kt; ka read), +bias ----
#pragma unroll
  for (int mt=0; mt<4; mt++){
    short8 af[4];
#pragma unroll
    for (int ks=0; ks<4; ks++)
      af[ks] = *(const short8*)(wkqv + (size_t)((mt+4)*16 + lr)*128 + ks*32 + lk*8);
    float4 bq4 = *(const float4*)(bias + 64 + mt*16 + lk*4);
#pragma unroll
    for (int ct=0; ct<4; ct++){
      f32x4 a = (f32x4){0.f,0.f,0.f,0.f};
#pragma unroll
      for (int ks=0; ks<4; ks++)
        a = __builtin_amdgcn_mfma_f32_16x16x32_bf16(af[ks], xbf[ct][ks], a, 0,0,0);
      a[0]+=bq4.x; a[1]+=bq4.y; a[2]+=bq4.z; a[3]+=bq4.w;
      int d = ct*16 + lr;
      *(uint2*)(slot + d*128 + ((mt*32 + lk*8) ^ ((d&7)<<4))) =
        (uint2){pk2(a[0],a[1]), pk2(a[2],a[3])};
    }
  }
  // ---- qb frags from qt ----
  short8 qb[4][2];
#pragma unroll
  for (int jt=0; jt<4; jt++)
#pragma unroll
    for (int ks2=0; ks2<2; ks2++){
      int j = jt*16 + lr;
      qb[jt][ks2] = *(const short8*)(slot + j*128 + ((ks2*64 + lk*16) ^ ((j&7)<<4)));
    }

  // ---- GEMM1-V -> registers, +bias ----
  f32x4 vacc[4][4];
#pragma unroll
  for (int mt=0; mt<4; mt++){
    short8 af[4];
#pragma unroll
    for (int ks=0; ks<4; ks++)
      af[ks] = *(const short8*)(wkqv + (size_t)((mt+8)*16 + lr)*128 + ks*32 + lk*8);
    float4 bv4 = *(const float4*)(bias + 128 + mt*16 + lk*4);
#pragma unroll
    for (int ct=0; ct<4; ct++) vacc[mt][ct] = (f32x4){0.f,0.f,0.f,0.f};
#pragma unroll
    for (int ct=0; ct<4; ct++){
#pragma unroll
      for (int ks=0; ks<4; ks++)
        vacc[mt][ct] = __builtin_amdgcn_mfma_f32_16x16x32_bf16(af[ks], xbf[ct][ks], vacc[mt][ct], 0,0,0);
      vacc[mt][ct][0]+=bv4.x; vacc[mt][ct][1]+=bv4.y;
      vacc[mt][ct][2]+=bv4.z; vacc[mt][ct][3]+=bv4.w;
    }
  }
  // ---- scatter V -> vt[s'][i] (overwrites qt; qb read), scalar ----
#pragma unroll
  for (int m4=0; m4<4; m4++)
#pragma unroll
    for (int ct=0; ct<4; ct++)
#pragma unroll
      for (int e=0; e<4; e++){
        int sp = m4*16 + lk*4 + e, i = ct*16 + lr;
        *(u16*)(slot + sp*128 + ((i*2) ^ ((sp&7)<<4))) = f2bf(vacc[m4][ct][e]);
      }

  // ---- GEMM2: scores[i][j] = sum_s' K[s',i] Q[s',j] ----
  f32x4 sc4[4][4];
#pragma unroll
  for (int it=0; it<4; it++)
#pragma unroll
    for (int jt=0; jt<4; jt++) sc4[it][jt] = (f32x4){0.f,0.f,0.f,0.f};
#pragma unroll
  for (int it=0; it<4; it++)
#pragma unroll
    for (int jt=0; jt<4; jt++)
#pragma unroll
      for (int ks2=0; ks2<2; ks2++)
        sc4[it][jt] = __builtin_amdgcn_mfma_f32_16x16x32_bf16(ka[it][ks2], qb[jt][ks2], sc4[it][jt], 0,0,0);

  // ---- softmax over i per column j, fully in-register ----
#pragma unroll
  for (int jt=0; jt<4; jt++){
    float m = -1e30f;
#pragma unroll
    for (int it=0; it<4; it++)
#pragma unroll
      for (int e=0; e<4; e++) m = fmaxf(m, sc4[it][jt][e]);
    m = fmaxf(m, __shfl_xor(m, 16, 64));
    m = fmaxf(m, __shfl_xor(m, 32, 64));
    float ssum = 0.f;
#pragma unroll
    for (int it=0; it<4; it++)
#pragma unroll
      for (int e=0; e<4; e++){
        float p = __expf((sc4[it][jt][e] - m) * 0.125f);
        sc4[it][jt][e] = p; ssum += p;
      }
    ssum += __shfl_xor(ssum, 16, 64);
    ssum += __shfl_xor(ssum, 32, 64);
    float inv = 1.0f / ssum;
#pragma unroll
    for (int it=0; it<4; it++)
#pragma unroll
      for (int e=0; e<4; e++) sc4[it][jt][e] *= inv;
  }

  // ---- va frags from vt (must precede a_t overwrite) ----
  short8 va[4][2];
#pragma unroll
  for (int st=0; st<4; st++)
#pragma unroll
    for (int ks2=0; ks2<2; ks2++){
      int s2 = st*16 + lr;
      va[st][ks2] = *(const short8*)(slot + s2*128 + ((ks2*64 + lk*16) ^ ((s2&7)<<4)));
    }
  // ---- a_t[j][i] <- sc4 (overwrites vt; va read), packed b64 ----
#pragma unroll
  for (int jt=0; jt<4; jt++){
    int j = jt*16 + lr;
#pragma unroll
    for (int it=0; it<4; it++){
      *(uint2*)(slot + j*128 + ((it*32 + lk*8) ^ ((j&7)<<4))) =
        (uint2){pk2(sc4[it][jt][0], sc4[it][jt][1]),
                pk2(sc4[it][jt][2], sc4[it][jt][3])};
    }
  }
  // ---- ab frags from a_t ----
  short8 ab[4][2];
#pragma unroll
  for (int jt=0; jt<4; jt++)
#pragma unroll
    for (int ks2=0; ks2<2; ks2++){
      int j = jt*16 + lr;
      ab[jt][ks2] = *(const short8*)(slot + j*128 + ((ks2*64 + lk*16) ^ ((j&7)<<4)));
    }

  // ---- GEMM3: attn[s'][j] = sum_i V[s'][i] a[i][j] ----
  f32x4 at4[4][4];
#pragma unroll
  for (int st=0; st<4; st++)
#pragma unroll
    for (int jt=0; jt<4; jt++) at4[st][jt] = (f32x4){0.f,0.f,0.f,0.f};
#pragma unroll
  for (int st=0; st<4; st++)
#pragma unroll
    for (int jt=0; jt<4; jt++)
#pragma unroll
      for (int ks2=0; ks2<2; ks2++)
        at4[st][jt] = __builtin_amdgcn_mfma_f32_16x16x32_bf16(va[st][ks2], ab[jt][ks2], at4[st][jt], 0,0,0);
  // ---- attn_t[d=j][s'] <- at4 (overwrites a_t; ab read), packed b64 ----
#pragma unroll
  for (int st=0; st<4; st++)
#pragma unroll
    for (int jt=0; jt<4; jt++){
      int d = jt*16 + lr;
      *(uint2*)(slot + d*128 + ((st*32 + lk*8) ^ ((d&7)<<4))) =
        (uint2){pk2(at4[st][jt][0], at4[st][jt][1]), pk2(at4[st][jt][2], at4[st][jt][3])};
    }
  // ---- tb frags from attn_t (needed for BOTH halves; read before o_slab overwrite) ----
  short8 tb[4][2];
#pragma unroll
  for (int dt=0; dt<4; dt++)
#pragma unroll
    for (int ks2=0; ks2<2; ks2++){
      int d = dt*16 + lr;
      tb[dt][ks2] = *(const short8*)(slot + d*128 + ((ks2*64 + lk*16) ^ ((d&7)<<4)));
    }

  // ---- GEMM4 + residual in two c-halves; o_slab half overwrites slot, then store ----
  u16* og = out_pre + (size_t)n*8192;
#pragma unroll
  for (int hf=0; hf<2; hf++){
#pragma unroll
    for (int mt=0; mt<4; mt++){
      short8 wa[2];
#pragma unroll
      for (int ks2=0; ks2<2; ks2++)
        wa[ks2] = *(const short8*)(wo + (size_t)((hf*4+mt)*16 + lr)*64 + ks2*32 + lk*8);
      f32x4 oa[4];
#pragma unroll
      for (int dt=0; dt<4; dt++) oa[dt] = (f32x4){0.f,0.f,0.f,0.f};
#pragma unroll
      for (int dt=0; dt<4; dt++)
#pragma unroll
        for (int ks2=0; ks2<2; ks2++)
          oa[dt] = __builtin_amdgcn_mfma_f32_16x16x32_bf16(wa[ks2], tb[dt][ks2], oa[dt], 0,0,0);
      // residual: raw x at [d = dt*16+lr][c = hf*64 + mt*16 + lk*4 + e]
#pragma unroll
      for (int dt=0; dt<4; dt++){
        ushort4 xv = *(const ushort4*)(xg + (size_t)(dt*16+lr)*128 + hf*64 + mt*16 + lk*4);
        oa[dt][0] += bf2f(xv.x);
        oa[dt][1] += bf2f(xv.y);
        oa[dt][2] += bf2f(xv.z);
        oa[dt][3] += bf2f(xv.w);
      }
#pragma unroll
      for (int dt=0; dt<4; dt++)
#pragma unroll
        for (int e=0; e<4; e++){
          int cl = mt*16 + lk*4 + e, d = dt*16 + lr;
          *(u16*)(slot + cl*128 + ((d*2) ^ ((cl&7)<<4))) = f2bf(oa[dt][e]);
        }
    }
    // coalesced store of this half: out_pre[n][hf*64 + cc][d]
#pragma unroll
    for (int r=0;r<8;r++){
      int j = r*64 + lane;          // j = cc*8 + o (cc 0..63, o = d-octet)
      int cc = j>>3, o = j&7;
      uint4 v = *(const uint4*)(slot + cc*128 + ((o*16) ^ ((cc&7)<<4)));
      *(uint4*)(og + hf*4096 + j*8) = v;
    }
  }
}

// ---------------- K4: out = untranspose(out_pre) (residual already folded in) ----------------
__global__ __launch_bounds__(256) void k_merge(const u16* out_pre, float* out){
  __shared__ u16 lm[32*512];   // 32 KB
  int t = threadIdx.x;
  int bid = blockIdx.x;
  int bh = bid>>2, cq = bid&3;
  int b = bh>>5, h = bh&31;
  int n0 = bh*32;
  int cbase = cq*32;
  int s = t>>3, q = t&7;
  for (int cc=0; cc<4; cc++){
    int cb = cbase + cc*8;
    {
      int n = s;
      int oq = q ^ ((n>>3)&3);
      bool swp = (n & 4) != 0;
#pragma unroll
      for (int i=0;i<8;i++){
        uint4 raw = *(const uint4*)(out_pre + (size_t)(n0+n)*8192 + (cb+i)*64 + q*8);
        if (swp){ u32 tx=raw.x, ty=raw.y; raw.x=raw.z; raw.y=raw.w; raw.z=tx; raw.w=ty; }
        *(uint4*)&lm[n*512 + i*64 + oq*8] = raw;
      }
    }
    __syncthreads();
    {
      int w4 = q*4;
#pragma unroll
      for (int g=0; g<16; g++){
        int row = g*32 + s;
        int ci = row>>6, d = row&63;
        size_t gi = ((size_t)((b*128 + cb + ci)*64 + d))*1024 + h*32 + w4;
        float4 ov;
        ov.x = bf2f(lm[(w4+0)*512 + (row ^ ((w4+0)&28))]);
        ov.y = bf2f(lm[(w4+1)*512 + (row ^ ((w4+1)&28))]);
        ov.z = bf2f(lm[(w4+2)*512 + (row ^ ((w4+2)&28))]);
        ov.w = bf2f(lm[(w4+3)*512 + (row ^ ((w4+3)&28))]);
        *(float4*)(out + gi) = ov;
      }
    }
    __syncthreads();
  }
}

extern "C" void kernel_launch(void* const* d_in, const int* in_sizes, int n_in,
                              void* d_out, int out_size, void* d_ws, size_t ws_size,
                              hipStream_t stream){
  const float* x     = (const float*)d_in[0];
  const float* Wk    = (const float*)d_in[1];
  const float* Wq    = (const float*)d_in[2];
  const float* Wv    = (const float*)d_in[3];
  const float* Wo    = (const float*)d_in[4];
  const float* gamma = (const float*)d_in[5];
  const float* beta  = (const float*)d_in[6];
  float* out = (float*)d_out;
  char* ws = (char*)d_ws;

  float* part  = (float*)(ws + WS_PART);
  float* bias  = (float*)(ws + WS_BIAS);
  u16* wkqv  = (u16*)(ws + WS_WKQV);
  u16* wo_bf = (u16*)(ws + WS_WO);
  u16* outp  = (u16*)(ws + WS_OUTP);
  u16* x_t   = (u16*)d_out;   // scratch in d_out; dead before k_merge writes

  k_zero    <<<8,    256, 0, stream>>>(part);
  k_stats_t <<<2048, 256, 0, stream>>>(x, x_t, part);
  k_finalize<<<1,    256, 0, stream>>>(part, gamma, beta, Wk, Wq, Wv, Wo, wkqv, wo_bf, bias);
  k_attn    <<<2048, 256, 0, stream>>>(x_t, wkqv, wo_bf, bias, outp);
  k_merge   <<<1024, 256, 0, stream>>>(outp, out);
}